// Round 1
// baseline (97.129 us; speedup 1.0000x reference)
//
#include <hip/hip_runtime.h>
#include <math.h>

#define B_ 16
#define L_ 1024
#define D_ 8
#define IMG 224
#define PIX (IMG*IMG)        /* 50176 */
#define NBD (B_*D_)          /* 128 */

/* ---- workspace layout ----
   uint slots (atomic ordered-float min/max):
     [0]        min over x
     [1..128]   min per (b,d) of cos_sum
     [129]      min over resized g
     [130]      max over x
     [131..258] max per (b,d)
     [259]      max over g
   float region:
     OFF_A    : a[128]     = inv/(8)   per (b,d)
     OFF_BIAS : bias[16]   = sum_d lo*inv/8
     OFF_CS   : cs[B][L][16]  (c[0..7], s[0..7])  -- 1 MB
     OFF_G    : g[B][PIX]                         -- 3.2 MB
*/
#define SLOT_MIN_X   0
#define SLOT_MIN_BD  1
#define SLOT_MIN_G   129
#define SLOT_MAX_X   130
#define SLOT_MAX_BD  131
#define SLOT_MAX_G   259

#define OFF_A    512
#define OFF_BIAS 640
#define OFF_CS   1024
#define OFF_G    (OFF_CS + B_*L_*16)   /* 263168 */

__device__ __forceinline__ unsigned fkey(float f) {
    unsigned u = __float_as_uint(f);
    return (u & 0x80000000u) ? ~u : (u | 0x80000000u);
}
__device__ __forceinline__ float funkey(unsigned k) {
    unsigned u = (k & 0x80000000u) ? (k & 0x7FFFFFFFu) : ~k;
    return __uint_as_float(u);
}

__device__ __forceinline__ void block_minmax_atomic(
    float mn, float mx, float* red, unsigned* smin, unsigned* smax) {
    #pragma unroll
    for (int off = 32; off > 0; off >>= 1) {
        mn = fminf(mn, __shfl_down(mn, off));
        mx = fmaxf(mx, __shfl_down(mx, off));
    }
    const int lane = threadIdx.x & 63;
    const int wave = threadIdx.x >> 6;
    const int nw   = blockDim.x >> 6;
    if (lane == 0) { red[wave*2] = mn; red[wave*2+1] = mx; }
    __syncthreads();
    if (threadIdx.x == 0) {
        for (int w = 1; w < nw; ++w) {
            mn = fminf(mn, red[w*2]);
            mx = fmaxf(mx, red[w*2+1]);
        }
        atomicMin(smin, fkey(mn));
        atomicMax(smax, fkey(mx));
    }
}

/* reset atomic slots every call (harness poisons ws once, never re-poisons) */
__global__ void k_init(unsigned* wsu) {
    int t = threadIdx.x;
    if (t < 130)      wsu[t] = 0xFFFFFFFFu;  /* mins  */
    else if (t < 260) wsu[t] = 0u;           /* maxes */
}

/* global min/max of x: 131072 floats = 32768 float4, 128 blocks x 256 thr */
__global__ __launch_bounds__(256) void k_xminmax(const float4* __restrict__ x,
                                                 unsigned* wsu) {
    __shared__ float red[8];
    int g = blockIdx.x*256 + threadIdx.x;
    float4 v = x[g];
    float mn = fminf(fminf(v.x, v.y), fminf(v.z, v.w));
    float mx = fmaxf(fmaxf(v.x, v.y), fmaxf(v.z, v.w));
    block_minmax_atomic(mn, mx, red, wsu + SLOT_MIN_X, wsu + SLOT_MAX_X);
}

/* c = clip(2*(x-lo)/(hi-lo+eps)-1), s = sqrt(1-c^2); store [b][l][{c8,s8}] */
__global__ __launch_bounds__(256) void k_cs(const float* __restrict__ x,
                                            const unsigned* wsu, float* wsf) {
    int e = blockIdx.x*256 + threadIdx.x;          /* [0,131072), = ((b*L+l)*8+d) */
    float lo = funkey(wsu[SLOT_MIN_X]);
    float hi = funkey(wsu[SLOT_MAX_X]);
    float r  = hi - lo;
    float xv = x[e];
    float xn = (r < 1e-8f) ? -1.0f : ((xv - lo) / (r + 1e-8f)) * 2.0f - 1.0f;
    xn = fminf(fmaxf(xn, -1.0f + 1e-6f), 1.0f - 1e-6f);
    float c = xn;
    float s = sqrtf(fmaxf(1.0f - c*c, 0.0f));
    int b = e >> 13, rem = e & 8191;
    int l = rem >> 3, d = rem & 7;
    float* base = wsf + OFF_CS + (size_t)(b*L_ + l)*16;
    base[d]     = c;
    base[8 + d] = s;
}

/* per-(b,d) min/max of cos_sum[i,j] = c_i c_j - s_i s_j, brute force over 1M
   pairs. 2 blocks per bd (256 blocks), each thread owns 2 i-rows, j via
   float4 LDS reads. */
__global__ __launch_bounds__(256) void k_pair(const float* __restrict__ wsf,
                                              unsigned* wsu) {
    __shared__ __align__(16) float lc[L_];
    __shared__ __align__(16) float ls[L_];
    __shared__ float red[8];
    int bd = blockIdx.x >> 1;
    int half = blockIdx.x & 1;
    int b = bd >> 3, d = bd & 7;
    const float* cs = wsf + OFF_CS + (size_t)b*L_*16;
    #pragma unroll
    for (int k = 0; k < 4; ++k) {
        int l = threadIdx.x + k*256;
        lc[l] = cs[(size_t)l*16 + d];
        ls[l] = cs[(size_t)l*16 + 8 + d];
    }
    __syncthreads();
    int i0 = half*512 + threadIdx.x;
    int i1 = i0 + 256;
    float c0 = lc[i0], s0 = ls[i0];
    float c1 = lc[i1], s1 = ls[i1];
    float mn = 1e30f, mx = -1e30f;
    const float4* lcv = (const float4*)lc;
    const float4* lsv = (const float4*)ls;
    #pragma unroll 4
    for (int j4 = 0; j4 < L_/4; ++j4) {
        float4 cj = lcv[j4], sj = lsv[j4];
        float v;
        v = c0*cj.x - s0*sj.x; mn = fminf(mn, v); mx = fmaxf(mx, v);
        v = c0*cj.y - s0*sj.y; mn = fminf(mn, v); mx = fmaxf(mx, v);
        v = c0*cj.z - s0*sj.z; mn = fminf(mn, v); mx = fmaxf(mx, v);
        v = c0*cj.w - s0*sj.w; mn = fminf(mn, v); mx = fmaxf(mx, v);
        v = c1*cj.x - s1*sj.x; mn = fminf(mn, v); mx = fmaxf(mx, v);
        v = c1*cj.y - s1*sj.y; mn = fminf(mn, v); mx = fmaxf(mx, v);
        v = c1*cj.z - s1*sj.z; mn = fminf(mn, v); mx = fmaxf(mx, v);
        v = c1*cj.w - s1*sj.w; mn = fminf(mn, v); mx = fmaxf(mx, v);
    }
    block_minmax_atomic(mn, mx, red, wsu + SLOT_MIN_BD + bd, wsu + SLOT_MAX_BD + bd);
}

/* a[bd] = inv/8 (0 if degenerate), bias[b] = sum_d lo*inv/8 */
__global__ void k_coef(const unsigned* wsu, float* wsf) {
    __shared__ float terms[NBD];
    int t = threadIdx.x;                 /* 128 threads, one per (b,d) */
    float lo = funkey(wsu[SLOT_MIN_BD + t]);
    float hi = funkey(wsu[SLOT_MAX_BD + t]);
    float r  = hi - lo;
    float inv = (r < 1e-8f) ? 0.0f : 1.0f / (r + 1e-8f);
    wsf[OFF_A + t] = inv * 0.125f;
    terms[t] = lo * inv * 0.125f;
    __syncthreads();
    if (t < B_) {
        float s = 0.f;
        #pragma unroll
        for (int d = 0; d < 8; ++d) s += terms[t*8 + d];
        wsf[OFF_BIAS + t] = s;
    }
}

/* resize: sample gaf-mean directly via separable bilinear of (c,s) vectors;
   also reduce global min/max of the resized image. */
__global__ __launch_bounds__(256) void k_resize(float* wsf, unsigned* wsu) {
    __shared__ float red[8];
    int pix = blockIdx.x*256 + threadIdx.x;     /* [0, 16*50176) */
    int b  = pix / PIX;
    int p  = pix - b*PIX;
    int oy = p / IMG;
    int ox = p - oy*IMG;
    const float SC = 1024.0f / 224.0f;
    float syf = (oy + 0.5f)*SC - 0.5f;
    float sxf = (ox + 0.5f)*SC - 0.5f;
    int iy0 = (int)floorf(syf);
    int ix0 = (int)floorf(sxf);
    float fy = syf - (float)iy0;
    float fx = sxf - (float)ix0;
    /* interior for 1024->224; clamp defensively */
    iy0 = max(0, min(iy0, L_-2));
    ix0 = max(0, min(ix0, L_-2));

    const float4* csv = (const float4*)(wsf + OFF_CS);
    size_t ry = (size_t)(b*L_ + iy0)*4;
    size_t rx = (size_t)(b*L_ + ix0)*4;
    float4 cy0a = csv[ry+0], cy0b = csv[ry+1], sy0a = csv[ry+2], sy0b = csv[ry+3];
    float4 cy1a = csv[ry+4], cy1b = csv[ry+5], sy1a = csv[ry+6], sy1b = csv[ry+7];
    float4 cx0a = csv[rx+0], cx0b = csv[rx+1], sx0a = csv[rx+2], sx0b = csv[rx+3];
    float4 cx1a = csv[rx+4], cx1b = csv[rx+5], sx1a = csv[rx+6], sx1b = csv[rx+7];
    const float4* av = (const float4*)(wsf + OFF_A + b*8);
    float4 aa = av[0], ab = av[1];

    float acc = 0.f;
#define TERM(CY0,CY1,SY0,SY1,CX0,CX1,SX0,SX1,A) do { \
        float hcy = CY0 + fy*(CY1-CY0); \
        float hsy = SY0 + fy*(SY1-SY0); \
        float hcx = CX0 + fx*(CX1-CX0); \
        float hsx = SX0 + fx*(SX1-SX0); \
        acc += (A)*(hcy*hcx - hsy*hsx); \
    } while (0)
    TERM(cy0a.x, cy1a.x, sy0a.x, sy1a.x, cx0a.x, cx1a.x, sx0a.x, sx1a.x, aa.x);
    TERM(cy0a.y, cy1a.y, sy0a.y, sy1a.y, cx0a.y, cx1a.y, sx0a.y, sx1a.y, aa.y);
    TERM(cy0a.z, cy1a.z, sy0a.z, sy1a.z, cx0a.z, cx1a.z, sx0a.z, sx1a.z, aa.z);
    TERM(cy0a.w, cy1a.w, sy0a.w, sy1a.w, cx0a.w, cx1a.w, sx0a.w, sx1a.w, aa.w);
    TERM(cy0b.x, cy1b.x, sy0b.x, sy1b.x, cx0b.x, cx1b.x, sx0b.x, sx1b.x, ab.x);
    TERM(cy0b.y, cy1b.y, sy0b.y, sy1b.y, cx0b.y, cx1b.y, sx0b.y, sx1b.y, ab.y);
    TERM(cy0b.z, cy1b.z, sy0b.z, sy1b.z, cx0b.z, cx1b.z, sx0b.z, sx1b.z, ab.z);
    TERM(cy0b.w, cy1b.w, sy0b.w, sy1b.w, cx0b.w, cx1b.w, sx0b.w, sx1b.w, ab.w);
#undef TERM
    float g = acc - wsf[OFF_BIAS + b];
    wsf[OFF_G + pix] = g;
    block_minmax_atomic(g, g, red, wsu + SLOT_MIN_G, wsu + SLOT_MAX_G);
}

/* final: out = (g - gmin) / (gmax - gmin + 1e-6), replicated to 3 channels */
__global__ __launch_bounds__(256) void k_out(const float* __restrict__ wsf,
                                             const unsigned* __restrict__ wsu,
                                             float* __restrict__ out) {
    int idx = blockIdx.x*256 + threadIdx.x;     /* [0, 16*50176) */
    float gmin = funkey(wsu[SLOT_MIN_G]);
    float gmax = funkey(wsu[SLOT_MAX_G]);
    float scale = 1.0f / ((gmax - gmin) + 1e-6f);
    float v = (wsf[OFF_G + idx] - gmin) * scale;
    int b = idx / PIX;
    int p = idx - b*PIX;
    float* ob = out + (size_t)b*(3*PIX) + p;
    ob[0]     = v;
    ob[PIX]   = v;
    ob[2*PIX] = v;
}

extern "C" void kernel_launch(void* const* d_in, const int* in_sizes, int n_in,
                              void* d_out, int out_size, void* d_ws, size_t ws_size,
                              hipStream_t stream) {
    const float* x  = (const float*)d_in[0];
    float* out      = (float*)d_out;
    unsigned* wsu   = (unsigned*)d_ws;
    float* wsf      = (float*)d_ws;

    k_init   <<<1,    512, 0, stream>>>(wsu);
    k_xminmax<<<128,  256, 0, stream>>>((const float4*)x, wsu);
    k_cs     <<<512,  256, 0, stream>>>(x, wsu, wsf);
    k_pair   <<<NBD*2,256, 0, stream>>>(wsf, wsu);
    k_coef   <<<1,    128, 0, stream>>>(wsu, wsf);
    k_resize <<<(B_*PIX)/256, 256, 0, stream>>>(wsf, wsu);
    k_out    <<<(B_*PIX)/256, 256, 0, stream>>>(wsf, wsu, out);
}

// Round 2
// 45.591 us; speedup vs baseline: 2.1305x; 2.1305x over previous
//
#include <hip/hip_runtime.h>
#include <math.h>

#define B_ 16
#define L_ 1024
#define D_ 8
#define IMG 224
#define PIX (IMG*IMG)        /* 50176 */
#define NBD (B_*D_)          /* 128 */

/* ---- workspace layout ----
   uint slots (atomic ordered-float min/max):
     [0]        min over x
     [1..128]   min per (b,d) of cos_sum
     [129]      min over resized g
     [130]      max over x
     [131..258] max per (b,d)
     [259]      max over g
   float region:
     OFF_A    : a[128]  = inv/8 per (b,d)
     OFF_BIAS : bias[16]
     OFF_T    : tbl[B][224][16]  (lerped c[0..7], s[0..7] at the 224 sample
                                  positions; same table serves x and y axes)
     OFF_G    : g[B][224][224]
*/
#define SLOT_MIN_X   0
#define SLOT_MIN_BD  1
#define SLOT_MIN_G   129
#define SLOT_MAX_X   130
#define SLOT_MAX_BD  131
#define SLOT_MAX_G   259

#define OFF_A    512
#define OFF_BIAS 640
#define OFF_T    768                     /* 16*224*16 = 57344 floats */
#define OFF_G    58368                   /* 16*50176  = 802816 floats */

__device__ __forceinline__ unsigned fkey(float f) {
    unsigned u = __float_as_uint(f);
    return (u & 0x80000000u) ? ~u : (u | 0x80000000u);
}
__device__ __forceinline__ float funkey(unsigned k) {
    unsigned u = (k & 0x80000000u) ? (k & 0x7FFFFFFFu) : ~k;
    return __uint_as_float(u);
}

__device__ __forceinline__ void block_minmax_atomic(
    float mn, float mx, float* red, unsigned* smin, unsigned* smax) {
    #pragma unroll
    for (int off = 32; off > 0; off >>= 1) {
        mn = fminf(mn, __shfl_down(mn, off));
        mx = fmaxf(mx, __shfl_down(mx, off));
    }
    const int lane = threadIdx.x & 63;
    const int wave = threadIdx.x >> 6;
    const int nw   = blockDim.x >> 6;
    if (lane == 0) { red[wave*2] = mn; red[wave*2+1] = mx; }
    __syncthreads();
    if (threadIdx.x == 0) {
        for (int w = 1; w < nw; ++w) {
            mn = fminf(mn, red[w*2]);
            mx = fmaxf(mx, red[w*2+1]);
        }
        atomicMin(smin, fkey(mn));
        atomicMax(smax, fkey(mx));
    }
}

/* normalization coefs from global x min/max: xn = x*sc + sh, then clip */
__device__ __forceinline__ void xnorm_coefs(const unsigned* wsu,
                                            float& sc, float& sh) {
    float lo = funkey(wsu[SLOT_MIN_X]);
    float hi = funkey(wsu[SLOT_MAX_X]);
    float r  = hi - lo;
    if (r < 1e-8f) { sc = 0.0f; sh = -1.0f; }
    else           { sc = 2.0f / (r + 1e-8f); sh = -lo * sc - 1.0f; }
}
__device__ __forceinline__ float cclip(float xn) {
    return fminf(fmaxf(xn, -1.0f + 1e-6f), 1.0f - 1e-6f);
}

/* reset atomic slots every call (harness poisons ws once, never re-poisons) */
__global__ void k_init(unsigned* wsu) {
    int t = threadIdx.x;
    if (t < 130)      wsu[t] = 0xFFFFFFFFu;  /* mins  */
    else if (t < 260) wsu[t] = 0u;           /* maxes */
}

/* global min/max of x: 131072 floats = 32768 float4, 128 blocks x 256 thr */
__global__ __launch_bounds__(256) void k_xminmax(const float4* __restrict__ x,
                                                 unsigned* wsu) {
    __shared__ float red[8];
    int g = blockIdx.x*256 + threadIdx.x;
    float4 v = x[g];
    float mn = fminf(fminf(v.x, v.y), fminf(v.z, v.w));
    float mx = fmaxf(fmaxf(v.x, v.y), fmaxf(v.z, v.w));
    block_minmax_atomic(mn, mx, red, wsu + SLOT_MIN_X, wsu + SLOT_MAX_X);
}

/* per-(b,d) min/max of cos_sum[i,j] = c_i c_j - s_i s_j.
   512 blocks: bd = blk>>2, j-quarter = blk&3. 256 thr, 4 i-rows/thread.
   (c,s) computed inline from x — no staging kernel needed. */
__global__ __launch_bounds__(256) void k_pair(const float* __restrict__ x,
                                              unsigned* wsu) {
    __shared__ __align__(16) float lcq[256];
    __shared__ __align__(16) float lsq[256];
    __shared__ float red[8];
    int bd = blockIdx.x >> 2;
    int jq = blockIdx.x & 3;
    int b = bd >> 3, d = bd & 7;
    float sc, sh; xnorm_coefs(wsu, sc, sh);
    int t = threadIdx.x;
    {
        float xv = x[((size_t)(b*L_ + jq*256 + t))*8 + d];
        float c  = cclip(xv*sc + sh);
        lcq[t] = c;
        lsq[t] = sqrtf(fmaxf(1.0f - c*c, 0.0f));
    }
    float ci[4], si[4];
    #pragma unroll
    for (int k = 0; k < 4; ++k) {
        float xv = x[((size_t)(b*L_ + t + k*256))*8 + d];
        float c  = cclip(xv*sc + sh);
        ci[k] = c;
        si[k] = sqrtf(fmaxf(1.0f - c*c, 0.0f));
    }
    __syncthreads();
    float mn = 1e30f, mx = -1e30f;
    const float4* lcv = (const float4*)lcq;
    const float4* lsv = (const float4*)lsq;
    #pragma unroll 4
    for (int j4 = 0; j4 < 64; ++j4) {
        float4 cj = lcv[j4], sj = lsv[j4];
        #pragma unroll
        for (int k = 0; k < 4; ++k) {
            float v0 = ci[k]*cj.x - si[k]*sj.x;
            float v1 = ci[k]*cj.y - si[k]*sj.y;
            float v2 = ci[k]*cj.z - si[k]*sj.z;
            float v3 = ci[k]*cj.w - si[k]*sj.w;
            mn = fminf(mn, fminf(fminf(v0, v1), fminf(v2, v3)));
            mx = fmaxf(mx, fmaxf(fmaxf(v0, v1), fmaxf(v2, v3)));
        }
    }
    block_minmax_atomic(mn, mx, red, wsu + SLOT_MIN_BD + bd, wsu + SLOT_MAX_BD + bd);
}

/* blocks 0..223: build sample table tbl[b][o][16] = lerped (c,s) at the 224
   half-pixel positions. block 224: compute a[bd], bias[b] from pair results. */
__global__ __launch_bounds__(256) void k_tablecoef(const float* __restrict__ x,
                                                   const unsigned* __restrict__ wsu,
                                                   float* wsf) {
    if (blockIdx.x == 224) {
        __shared__ float terms[NBD];
        int t = threadIdx.x;
        if (t < NBD) {
            float lo = funkey(wsu[SLOT_MIN_BD + t]);
            float hi = funkey(wsu[SLOT_MAX_BD + t]);
            float rr = hi - lo;
            float inv = (rr < 1e-8f) ? 0.0f : 1.0f / (rr + 1e-8f);
            wsf[OFF_A + t] = inv * 0.125f;
            terms[t] = lo * inv * 0.125f;
        }
        __syncthreads();
        if (t < B_) {
            float s = 0.f;
            #pragma unroll
            for (int d = 0; d < 8; ++d) s += terms[t*8 + d];
            wsf[OFF_BIAS + t] = s;
        }
        return;
    }
    int idx = blockIdx.x*256 + threadIdx.x;      /* [0, 57344) */
    int b   = idx / 3584;
    int rem = idx - b*3584;
    int o   = rem >> 4;
    int k   = rem & 15;
    int d   = k & 7;
    float sc, sh; xnorm_coefs(wsu, sc, sh);
    const float SC = 1024.0f / 224.0f;
    float syf = (o + 0.5f)*SC - 0.5f;            /* in [1.78, 1021.2] */
    int   i0  = (int)floorf(syf);
    i0 = max(0, min(i0, L_ - 2));
    float f   = syf - (float)i0;
    float x0 = x[((size_t)(b*L_ + i0    ))*8 + d];
    float x1 = x[((size_t)(b*L_ + i0 + 1))*8 + d];
    float c0 = cclip(x0*sc + sh);
    float c1 = cclip(x1*sc + sh);
    float v0, v1;
    if (k < 8) { v0 = c0; v1 = c1; }
    else {
        v0 = sqrtf(fmaxf(1.0f - c0*c0, 0.0f));
        v1 = sqrtf(fmaxf(1.0f - c1*c1, 0.0f));
    }
    wsf[OFF_T + idx] = v0 + f*(v1 - v0);
}

/* resize compute: 512 blocks = 16 b x 32 strips of 7 rows. Thread = one ox.
   x-side (c,s) loaded coalesced (own ox entry), y-side via LDS broadcast. */
__global__ __launch_bounds__(256) void k_resize2(float* wsf, unsigned* wsu) {
    __shared__ float lds_y[112];                 /* 7 rows x 16 */
    __shared__ float red[8];
    int b     = blockIdx.x >> 5;
    int strip = blockIdx.x & 31;
    const float* tb = wsf + OFF_T + b*3584;
    int t = threadIdx.x;
    if (t < 112) lds_y[t] = tb[strip*112 + t];
    __syncthreads();
    int ox = min(t, 223);
    bool active = (t < 224);
    const float4* xt = (const float4*)(tb + ox*16);
    float4 cx0 = xt[0], cx1 = xt[1], sx0 = xt[2], sx1 = xt[3];
    const float4* av = (const float4*)(wsf + OFF_A + b*8);
    float4 a0 = av[0], a1 = av[1];
    float bias = wsf[OFF_BIAS + b];
    float mn = 1e30f, mx = -1e30f;
    #pragma unroll
    for (int rr = 0; rr < 7; ++rr) {
        const float* Y = lds_y + rr*16;
        float acc;
        acc  = (a0.x*Y[0])*cx0.x - (a0.x*Y[ 8])*sx0.x;
        acc += (a0.y*Y[1])*cx0.y - (a0.y*Y[ 9])*sx0.y;
        acc += (a0.z*Y[2])*cx0.z - (a0.z*Y[10])*sx0.z;
        acc += (a0.w*Y[3])*cx0.w - (a0.w*Y[11])*sx0.w;
        acc += (a1.x*Y[4])*cx1.x - (a1.x*Y[12])*sx1.x;
        acc += (a1.y*Y[5])*cx1.y - (a1.y*Y[13])*sx1.y;
        acc += (a1.z*Y[6])*cx1.z - (a1.z*Y[14])*sx1.z;
        acc += (a1.w*Y[7])*cx1.w - (a1.w*Y[15])*sx1.w;
        float g = acc - bias;
        if (active) {
            int oy = strip*7 + rr;
            wsf[OFF_G + ((size_t)(b*IMG + oy))*IMG + ox] = g;
            mn = fminf(mn, g);
            mx = fmaxf(mx, g);
        }
    }
    block_minmax_atomic(mn, mx, red, wsu + SLOT_MIN_G, wsu + SLOT_MAX_G);
}

/* final: out = (g - gmin) / (gmax - gmin + 1e-6), replicated to 3 channels */
__global__ __launch_bounds__(256) void k_out(const float* __restrict__ wsf,
                                             const unsigned* __restrict__ wsu,
                                             float* __restrict__ out) {
    int idx = blockIdx.x*256 + threadIdx.x;      /* [0, 16*50176) */
    float gmin = funkey(wsu[SLOT_MIN_G]);
    float gmax = funkey(wsu[SLOT_MAX_G]);
    float scale = 1.0f / ((gmax - gmin) + 1e-6f);
    float v = (wsf[OFF_G + idx] - gmin) * scale;
    int b = idx / PIX;
    int p = idx - b*PIX;
    float* ob = out + (size_t)b*(3*PIX) + p;
    ob[0]     = v;
    ob[PIX]   = v;
    ob[2*PIX] = v;
}

extern "C" void kernel_launch(void* const* d_in, const int* in_sizes, int n_in,
                              void* d_out, int out_size, void* d_ws, size_t ws_size,
                              hipStream_t stream) {
    const float* x  = (const float*)d_in[0];
    float* out      = (float*)d_out;
    unsigned* wsu   = (unsigned*)d_ws;
    float* wsf      = (float*)d_ws;

    k_init     <<<1,    512, 0, stream>>>(wsu);
    k_xminmax  <<<128,  256, 0, stream>>>((const float4*)x, wsu);
    k_pair     <<<512,  256, 0, stream>>>(x, wsu);
    k_tablecoef<<<225,  256, 0, stream>>>(x, wsu, wsf);
    k_resize2  <<<512,  256, 0, stream>>>(wsf, wsu);
    k_out      <<<(B_*PIX)/256, 256, 0, stream>>>(wsf, wsu, out);
}

// Round 3
// 38.702 us; speedup vs baseline: 2.5097x; 1.1780x over previous
//
#include <hip/hip_runtime.h>
#include <math.h>

#define B_ 16
#define L_ 1024
#define D_ 8
#define IMG 224
#define PIX (IMG*IMG)        /* 50176 */
#define NBD (B_*D_)          /* 128 */

/* ---- workspace layout ----
   uint slots:
     [0] min over resized g (ordered-key atomic)   [1] max over g
   float region:
     OFF_XPMIN: xpart_min[128]   (per-block partials, plain stores)
     OFF_XPMAX: xpart_max[128]
     OFF_SC/SH: global x-norm coefs (written by pairsort block 0)
     OFF_A    : a[128]    = inv/8 per (b,d)
     OFF_TERM : term[128] = lo*inv/8 per (b,d)
     OFF_T    : tbl[B][224][16]  (lerped c[0..7], s[0..7] at sample pos)
     OFF_G    : g[B][224][224]
*/
#define SLOT_MIN_G 0
#define SLOT_MAX_G 1
#define OFF_XPMIN  8
#define OFF_XPMAX  136
#define OFF_SC     264
#define OFF_SH     265
#define OFF_A      272
#define OFF_TERM   400
#define OFF_T      1024                  /* 16*224*16 = 57344 floats */
#define OFF_G      58368                 /* 16*50176  = 802816 floats */

__device__ __forceinline__ unsigned fkey(float f) {
    unsigned u = __float_as_uint(f);
    return (u & 0x80000000u) ? ~u : (u | 0x80000000u);
}
__device__ __forceinline__ float funkey(unsigned k) {
    unsigned u = (k & 0x80000000u) ? (k & 0x7FFFFFFFu) : ~k;
    return __uint_as_float(u);
}
__device__ __forceinline__ float cclip(float xn) {
    return fminf(fmaxf(xn, -1.0f + 1e-6f), 1.0f - 1e-6f);
}

/* block min/max -> red[0]=min, red[1]=max (all threads see it after return) */
template <int NTHR>
__device__ __forceinline__ void block_minmax_share(float mn, float mx, float* red) {
    #pragma unroll
    for (int off = 32; off > 0; off >>= 1) {
        mn = fminf(mn, __shfl_down(mn, off));
        mx = fmaxf(mx, __shfl_down(mx, off));
    }
    const int lane = threadIdx.x & 63;
    const int wave = threadIdx.x >> 6;
    if (lane == 0) { red[2 + wave*2] = mn; red[3 + wave*2] = mx; }
    __syncthreads();
    if (threadIdx.x == 0) {
        #pragma unroll
        for (int w = 1; w < NTHR/64; ++w) {
            mn = fminf(mn, red[2 + w*2]);
            mx = fmaxf(mx, red[3 + w*2]);
        }
        red[0] = mn; red[1] = mx;
    }
    __syncthreads();
}

/* K1: per-block x min/max partials (plain stores, no init needed);
   block 0 also resets the two g-atomic slots for this call. */
__global__ __launch_bounds__(256) void k_xpart(const float4* __restrict__ x,
                                               float* wsf, unsigned* wsu) {
    __shared__ float red[16];
    if (blockIdx.x == 0 && threadIdx.x == 0) {
        wsu[SLOT_MIN_G] = 0xFFFFFFFFu;
        wsu[SLOT_MAX_G] = 0u;
    }
    int g = blockIdx.x*256 + threadIdx.x;
    float4 v = x[g];
    float mn = fminf(fminf(v.x, v.y), fminf(v.z, v.w));
    float mx = fmaxf(fmaxf(v.x, v.y), fmaxf(v.z, v.w));
    block_minmax_share<256>(mn, mx, red);
    if (threadIdx.x == 0) {
        wsf[OFF_XPMIN + blockIdx.x] = red[0];
        wsf[OFF_XPMAX + blockIdx.x] = red[1];
    }
}

/* K2: one block per (b,d). Reduce x partials -> (sc,sh); load c-row to LDS;
   bitonic-sort a copy; analytic per-bd min/max of cos_sum:
     max = max(2*cmin^2-1, 2*cmax^2-1)          (diagonal extreme sums)
     min = min over i of cos at the two c-neighbors of -c_i  (sum nearest pi)
   Then write a[bd], term[bd] and this d-slice of the (c,s) sample table. */
__global__ __launch_bounds__(512) void k_pairsort(const float* __restrict__ x,
                                                  float* wsf) {
    __shared__ float corig[L_];
    __shared__ float sb[L_];
    __shared__ float red[32];
    const int bd = blockIdx.x;
    const int b = bd >> 3, d = bd & 7;
    const int t = threadIdx.x;

    /* global x min/max from 128 partials */
    float pmn = (t < 128) ? wsf[OFF_XPMIN + t] :  1e30f;
    float pmx = (t < 128) ? wsf[OFF_XPMAX + t] : -1e30f;
    block_minmax_share<512>(pmn, pmx, red);
    float lo = red[0], hi = red[1];
    float r  = hi - lo;
    float sc, sh;
    if (r < 1e-8f) { sc = 0.0f; sh = -1.0f; }
    else           { sc = 2.0f / (r + 1e-8f); sh = -lo*sc - 1.0f; }
    if (bd == 0 && t == 0) { wsf[OFF_SC] = sc; wsf[OFF_SH] = sh; }

    /* load this (b,d) row's c values */
    for (int i = t; i < L_; i += 512) {
        float c = cclip(x[((size_t)(b*L_ + i))*8 + d]*sc + sh);
        corig[i] = c;
        sb[i]    = c;
    }
    __syncthreads();

    /* bitonic sort sb ascending: 512 compare-exchanges per stage, 1/thread */
    for (int k = 2; k <= L_; k <<= 1) {
        for (int j = k >> 1; j > 0; j >>= 1) {
            int i = ((t & ~(j-1)) << 1) | (t & (j-1));
            int p = i | j;
            bool up = ((i & k) == 0);
            float a = sb[i], bvl = sb[p];
            if ((a > bvl) == up) { sb[i] = bvl; sb[p] = a; }
            __syncthreads();
        }
    }

    /* min: for each i, evaluate the two neighbors of -c_i in sorted order */
    float mnc = 1e30f;
    for (int ii = t; ii < L_; ii += 512) {
        float ci = sb[ii];
        float si = sqrtf(fmaxf(1.0f - ci*ci, 0.0f));
        float tgt = -ci;
        int lo2 = 0, hi2 = L_;
        #pragma unroll
        for (int it = 0; it < 10; ++it) {
            int mid = (lo2 + hi2) >> 1;
            if (sb[mid] < tgt) lo2 = mid + 1; else hi2 = mid;
        }
        int j0 = max(lo2 - 1, 0), j1 = min(lo2, L_ - 1);
        float cj = sb[j0], sj = sqrtf(fmaxf(1.0f - cj*cj, 0.0f));
        mnc = fminf(mnc, ci*cj - si*sj);
        cj = sb[j1]; sj = sqrtf(fmaxf(1.0f - cj*cj, 0.0f));
        mnc = fminf(mnc, ci*cj - si*sj);
    }
    float c0 = sb[0], cN = sb[L_-1];
    float mxc = fmaxf(2.0f*c0*c0 - 1.0f, 2.0f*cN*cN - 1.0f);
    __syncthreads();                /* protect red[] reuse */
    block_minmax_share<512>(mnc, -1e30f, red);
    if (t == 0) {
        float plo = red[0], phi = mxc;
        float rr  = phi - plo;
        float inv = (rr < 1e-8f) ? 0.0f : 1.0f / (rr + 1e-8f);
        wsf[OFF_A + bd]    = inv * 0.125f;
        wsf[OFF_TERM + bd] = plo * inv * 0.125f;
    }

    /* sample table: lerped (c,s) at the 224 half-pixel positions, d-slice */
    if (t < IMG) {
        const float SC = 1024.0f / 224.0f;
        float syf = (t + 0.5f)*SC - 0.5f;
        int   i0  = (int)floorf(syf);
        i0 = max(0, min(i0, L_ - 2));
        float f   = syf - (float)i0;
        float ca = corig[i0], cb = corig[i0+1];
        float sa = sqrtf(fmaxf(1.0f - ca*ca, 0.0f));
        float sbv = sqrtf(fmaxf(1.0f - cb*cb, 0.0f));
        size_t base = OFF_T + ((size_t)(b*IMG + t))*16;
        wsf[base + d]     = ca + f*(cb - ca);
        wsf[base + 8 + d] = sa + f*(sbv - sa);
    }
}

/* K3: resize compute. 512 blocks = 16 b x 32 strips of 7 rows; thread = ox.
   x-side (c,s) coalesced from table, y-side via 112-float LDS strip. */
__global__ __launch_bounds__(256) void k_resize(float* wsf, unsigned* wsu) {
    __shared__ float lds_y[112];
    __shared__ float red[16];
    int b     = blockIdx.x >> 5;
    int strip = blockIdx.x & 31;
    const float* tb = wsf + OFF_T + (size_t)b*IMG*16;
    int t = threadIdx.x;
    if (t < 112) lds_y[t] = tb[strip*112 + t];
    __syncthreads();
    int ox = min(t, IMG-1);
    bool active = (t < IMG);
    const float4* xt = (const float4*)(tb + ox*16);
    float4 cx0 = xt[0], cx1 = xt[1], sx0 = xt[2], sx1 = xt[3];
    const float4* av = (const float4*)(wsf + OFF_A + b*8);
    float4 a0 = av[0], a1 = av[1];
    float bias = 0.f;
    #pragma unroll
    for (int dd = 0; dd < 8; ++dd) bias += wsf[OFF_TERM + b*8 + dd];
    float mn = 1e30f, mx = -1e30f;
    #pragma unroll
    for (int rr = 0; rr < 7; ++rr) {
        const float* Y = lds_y + rr*16;
        float acc;
        acc  = (a0.x*Y[0])*cx0.x - (a0.x*Y[ 8])*sx0.x;
        acc += (a0.y*Y[1])*cx0.y - (a0.y*Y[ 9])*sx0.y;
        acc += (a0.z*Y[2])*cx0.z - (a0.z*Y[10])*sx0.z;
        acc += (a0.w*Y[3])*cx0.w - (a0.w*Y[11])*sx0.w;
        acc += (a1.x*Y[4])*cx1.x - (a1.x*Y[12])*sx1.x;
        acc += (a1.y*Y[5])*cx1.y - (a1.y*Y[13])*sx1.y;
        acc += (a1.z*Y[6])*cx1.z - (a1.z*Y[14])*sx1.z;
        acc += (a1.w*Y[7])*cx1.w - (a1.w*Y[15])*sx1.w;
        float g = acc - bias;
        if (active) {
            int oy = strip*7 + rr;
            wsf[OFF_G + ((size_t)(b*IMG + oy))*IMG + ox] = g;
            mn = fminf(mn, g);
            mx = fmaxf(mx, g);
        }
    }
    block_minmax_share<256>(mn, mx, red);
    if (t == 0) {
        atomicMin(wsu + SLOT_MIN_G, fkey(red[0]));
        atomicMax(wsu + SLOT_MAX_G, fkey(red[1]));
    }
}

/* K4: out = (g - gmin)/(gmax - gmin + 1e-6), x3 channels, float4-vectorized */
__global__ __launch_bounds__(256) void k_out(const float* __restrict__ wsf,
                                             const unsigned* __restrict__ wsu,
                                             float* __restrict__ out) {
    int idx = blockIdx.x*256 + threadIdx.x;      /* [0, 200704) float4 groups */
    float gmin = funkey(wsu[SLOT_MIN_G]);
    float gmax = funkey(wsu[SLOT_MAX_G]);
    float scale = 1.0f / ((gmax - gmin) + 1e-6f);
    float4 gv = ((const float4*)(wsf + OFF_G))[idx];
    float4 v;
    v.x = (gv.x - gmin)*scale;
    v.y = (gv.y - gmin)*scale;
    v.z = (gv.z - gmin)*scale;
    v.w = (gv.w - gmin)*scale;
    int b   = idx / (PIX/4);
    int rem = idx - b*(PIX/4);
    float4* ob = (float4*)(out + (size_t)b*3*PIX) + rem;
    ob[0]         = v;
    ob[PIX/4]     = v;
    ob[2*(PIX/4)] = v;
}

extern "C" void kernel_launch(void* const* d_in, const int* in_sizes, int n_in,
                              void* d_out, int out_size, void* d_ws, size_t ws_size,
                              hipStream_t stream) {
    const float* x  = (const float*)d_in[0];
    float* out      = (float*)d_out;
    unsigned* wsu   = (unsigned*)d_ws;
    float* wsf      = (float*)d_ws;

    k_xpart   <<<128, 256, 0, stream>>>((const float4*)x, wsf, wsu);
    k_pairsort<<<NBD, 512, 0, stream>>>(x, wsf);
    k_resize  <<<512, 256, 0, stream>>>(wsf, wsu);
    k_out     <<<(B_*PIX/4)/256, 256, 0, stream>>>(wsf, wsu, out);
}